// Round 9
// baseline (485.745 us; speedup 1.0000x reference)
//
#include <hip/hip_runtime.h>
#include <cstdint>
#include <cstddef>

// Problem constants (fixed by reference setup_inputs):
//   b=256, t=512, in_dim=30, hidden=512, n_cls=12, TAU=2, V_TH=1
#define NB 256
#define NT 512
#define IND 30
#define HID 512
#define NCLS 12
#define MAXREC 640      // per-b event record slots (16 B each, cnt<=4 per record)
#define NGRP 4          // t-chunks for the event-driven layer-2 scan
#define CHUNK 128       // NT / NGRP
#define WARM 32         // layer-2 warmup steps (0.5^32 reconvergence)
#define TT 64           // t-tile for the z/LIF pipeline
#define NTILE (NT / TT)

typedef float v2f __attribute__((ext_vector_type(2)));
typedef float v4f __attribute__((ext_vector_type(4)));
// x rows are 120 B -> only 4-B alignment guaranteed for vector loads.
typedef v4f v4f_u __attribute__((aligned(4)));
typedef v2f v2f_u __attribute__((aligned(4)));

struct XRow { v4f q0, q1, q2, q3, q4, q5, q6; v2f q7; };

__device__ __forceinline__ void load_row(const float* __restrict__ row, XRow& r) {
    r.q0 = *(const v4f_u*)(row +  0);
    r.q1 = *(const v4f_u*)(row +  4);
    r.q2 = *(const v4f_u*)(row +  8);
    r.q3 = *(const v4f_u*)(row + 12);
    r.q4 = *(const v4f_u*)(row + 16);
    r.q5 = *(const v4f_u*)(row + 20);
    r.q6 = *(const v4f_u*)(row + 24);
    r.q7 = *(const v2f_u*)(row + 28);
}

// ---------------------------------------------------------------------------
// W2 pair-transpose: W2Tp[d*256 + j] = {W2[j][d], W2[j+256][d]}
// ---------------------------------------------------------------------------
__global__ __launch_bounds__(256) void w2pt_kernel(
    const float* __restrict__ W2, v2f* __restrict__ W2Tp)
{
    __shared__ float ta[32][33];
    __shared__ float tb[32][33];
    const int d0 = blockIdx.x * 32;
    const int j0 = blockIdx.y * 32;
    const int tx = threadIdx.x & 31;
    const int ty = threadIdx.x >> 5;
    #pragma unroll
    for (int i = 0; i < 32; i += 8) {
        ta[ty + i][tx] = W2[(size_t)(j0 + ty + i) * HID + (d0 + tx)];
        tb[ty + i][tx] = W2[(size_t)(j0 + 256 + ty + i) * HID + (d0 + tx)];
    }
    __syncthreads();
    #pragma unroll
    for (int i = 0; i < 32; i += 8)
        W2Tp[(size_t)(d0 + ty + i) * 256 + (j0 + tx)] = v2f{ta[tx][ty + i], tb[tx][ty + i]};
}

// ---------------------------------------------------------------------------
// Fused per-b SNN kernel: 1024 threads = 16 waves (133 KB LDS -> 1 block/CU,
// 4 waves/SIMD, RA budget 128 VGPR -> no spill by construction).
//
// phase 1, per 64-t tile:
//   compute: wave w computes z[t=lane][h] for h in [32w, 32w+32):
//     x[t] per-lane in VGPRs (coalesced load, once per tile);
//     W1[h] wave-uniform -> s_load into SGPRs, double-buffered over h;
//     30 v_fma(vgpr_x, sgpr_w, acc) per h; ds_write z to padded LDS tile
//     zl[h*65 + t] (banks (h+t)%32: conflict-free writes AND reads).
//   scan: thread h (<512) runs 64 sequential LIF steps from LDS with
//     8-deep register prefetch; ballots -> global bitmap word (tid>>6).
//   No time-split/warmup for layer 1 - the block owns b's whole timeline.
// phases 2-4 (after fence): r8's proven tail - pack bitmap -> event records,
//   event-driven layer-2 LIF (4 t-chunks with 32-step warmup), head GEMV.
//   LDS arena is re-used (z tile is dead by then).
// ---------------------------------------------------------------------------
__global__ __launch_bounds__(1024) void snn_fused_kernel(
    const float* __restrict__ x,     // (NB, NT, IND)
    const float* __restrict__ W1,    // (HID, IND)
    const float* __restrict__ b1,    // (HID)
    const v2f*  __restrict__ W2Tp,   // (HID d, 256 j) pairs
    const float* __restrict__ b2,    // (HID)
    const float* __restrict__ Wh,    // (NCLS, HID)
    const float* __restrict__ bh,    // (NCLS)
    uint64_t* __restrict__ bmg,      // (NB, NT, 8) spike bitmap
    float* __restrict__ out)         // (NB, NCLS)
{
    __shared__ __align__(16) char arena[HID * 65 * 4];   // 133 KB
    float* zl = (float*)arena;                           // [h*65 + t]

    const int b    = blockIdx.x;
    const int tid  = threadIdx.x;
    const int lane = tid & 63;
    const int wv   = tid >> 6;            // wave 0..15
    const int h0   = wv * 32;             // compute-phase h range

    const float* __restrict__ xb = x + (size_t)b * NT * IND;

    float vv = 0.f;                       // layer-1 potential for h = tid (<512)

    // z for one (t=lane, h): 30 fma, 3 chains, W from (hopefully) SGPRs.
#define CZ(R, W, BIAS, DST) do {                                          \
        float a0 = (BIAS), a1 = 0.f, a2 = 0.f;                            \
        a0 = fmaf(R.q0.x, W[0], a0); a1 = fmaf(R.q0.y, W[1], a1);         \
        a2 = fmaf(R.q0.z, W[2], a2); a0 = fmaf(R.q0.w, W[3], a0);         \
        a1 = fmaf(R.q1.x, W[4], a1); a2 = fmaf(R.q1.y, W[5], a2);         \
        a0 = fmaf(R.q1.z, W[6], a0); a1 = fmaf(R.q1.w, W[7], a1);         \
        a2 = fmaf(R.q2.x, W[8], a2); a0 = fmaf(R.q2.y, W[9], a0);         \
        a1 = fmaf(R.q2.z, W[10], a1); a2 = fmaf(R.q2.w, W[11], a2);       \
        a0 = fmaf(R.q3.x, W[12], a0); a1 = fmaf(R.q3.y, W[13], a1);       \
        a2 = fmaf(R.q3.z, W[14], a2); a0 = fmaf(R.q3.w, W[15], a0);       \
        a1 = fmaf(R.q4.x, W[16], a1); a2 = fmaf(R.q4.y, W[17], a2);       \
        a0 = fmaf(R.q4.z, W[18], a0); a1 = fmaf(R.q4.w, W[19], a1);       \
        a2 = fmaf(R.q5.x, W[20], a2); a0 = fmaf(R.q5.y, W[21], a0);       \
        a1 = fmaf(R.q5.z, W[22], a1); a2 = fmaf(R.q5.w, W[23], a2);       \
        a0 = fmaf(R.q6.x, W[24], a0); a1 = fmaf(R.q6.y, W[25], a1);       \
        a2 = fmaf(R.q6.z, W[26], a2); a0 = fmaf(R.q6.w, W[27], a0);       \
        a1 = fmaf(R.q7.x, W[28], a1); a2 = fmaf(R.q7.y, W[29], a2);       \
        (DST) = (a0 + a1) + a2;                                           \
    } while (0)

#define LOADW(H, WD, BD) do {                                             \
        const float* _wr = W1 + (size_t)(H) * IND;                        \
        _Pragma("unroll")                                                 \
        for (int _j = 0; _j < IND; _j++) WD[_j] = _wr[_j];                \
        BD = b1[(H)];                                                     \
    } while (0)

    for (int tile = 0; tile < NTILE; tile++) {
        const int t0 = tile * TT;
        XRow xr;                                   // issued before the barrier:
        load_row(xb + (size_t)(t0 + lane) * IND, xr);  // overlaps prev scan
        __syncthreads();                           // prev tile's scan done

        {   // compute 32 h's, 2-way unrolled, W double-buffered (uniform)
            float wA[IND], wB[IND]; float bsA, bsB;
            LOADW(h0, wA, bsA);
            #pragma unroll 2
            for (int i = 0; i < 32; i += 2) {
                LOADW(h0 + i + 1, wB, bsB);
                float z0; CZ(xr, wA, bsA, z0);
                zl[(size_t)(h0 + i) * 65 + lane] = z0;
                if (i + 2 < 32) LOADW(h0 + i + 2, wA, bsA);
                float z1; CZ(xr, wB, bsB, z1);
                zl[(size_t)(h0 + i + 1) * 65 + lane] = z1;
            }
        }
        __syncthreads();                           // z tile ready

        if (tid < HID) {                           // scan: waves 0..7
            uint64_t* bout = bmg + ((size_t)b * NT + t0) * 8 + wv;
            float zb[8];
            #pragma unroll
            for (int k = 0; k < 8; k++) zb[k] = zl[(size_t)tid * 65 + k];
            #pragma unroll
            for (int base = 0; base < TT; base += 8) {
                float zn[8];
                if (base + 8 < TT) {
                    #pragma unroll
                    for (int k = 0; k < 8; k++)
                        zn[k] = zl[(size_t)tid * 65 + base + 8 + k];
                }
                #pragma unroll
                for (int k = 0; k < 8; k++) {
                    vv = vv + (zb[k] - vv) * 0.5f;      // charge (tau=2)
                    const bool sp = vv >= 1.0f;
                    const unsigned long long m = __ballot(sp);
                    if (sp) vv = 0.0f;                  // hard reset
                    if (lane == 0) bout[(size_t)(base + k) * 8] = m;
                }
                if (base + 8 < TT) {
                    #pragma unroll
                    for (int k = 0; k < 8; k++) zb[k] = zn[k];
                }
            }
        }
    }
#undef LOADW
#undef CZ

    __threadfence();       // publish bitmap stores
    __syncthreads();       // z tile dead; arena re-used below

    // ---- arena re-layout for phases 2-4 (25.6 KB of 133 KB) ---------------
    uint32_t* sbuf0  = (uint32_t*)arena;              // [512]
    uint32_t* sbuf1  = (uint32_t*)(arena + 2048);     // [512]
    uint16_t* rowoff = (uint16_t*)(arena + 4096);     // [512]
    uint4*    evl    = (uint4*)(arena + 5120);        // [MAXREC]
    float*    gcnt   = (float*)(arena + 15360);       // [NGRP][HID]
    float*    feat   = (float*)(arena + 23552);       // [HID]
    uint32_t* nrec_p = (uint32_t*)(arena + 25600);

    const int grp   = tid >> 8;           // 0..3
    const int tig   = tid & 255;
    const int tmain = grp * CHUNK;

    // ---- phase 2: pack bitmap -> event records ----------------------------
    uint64_t w0[8];
    int rcnt = 0;
    if (tid < NT) {
        const uint4* p = (const uint4*)(bmg + ((size_t)b * NT + tid) * 8);
        int cpop = 0;
        #pragma unroll
        for (int k = 0; k < 4; k++) {
            const uint4 q = p[k];
            w0[2 * k]     = (uint64_t)q.x | ((uint64_t)q.y << 32);
            w0[2 * k + 1] = (uint64_t)q.z | ((uint64_t)q.w << 32);
        }
        #pragma unroll
        for (int k = 0; k < 8; k++) cpop += __builtin_popcountll(w0[k]);
        rcnt = (cpop + 3) >> 2;
        sbuf0[tid] = (uint32_t)rcnt;
    }
    __syncthreads();
    uint32_t* sA = sbuf0; uint32_t* sB = sbuf1;
    for (int off = 1; off < NT; off <<= 1) {
        uint32_t a = 0;
        if (tid < NT) a = sA[tid] + (tid >= off ? sA[tid - off] : 0u);
        if (tid < NT) sB[tid] = a;
        __syncthreads();
        uint32_t* t_ = sA; sA = sB; sB = t_;
    }
    int excl = 0;
    if (tid < NT) {
        excl = (int)sA[tid] - rcnt;
        rowoff[tid] = (uint16_t)(excl < 65535 ? excl : 65535);
        if (tid == NT - 1) *nrec_p = sA[NT - 1];
    }
    if (tid < NT) {
        int slot = excl, kk = 0; uint64_t ww = 0;
        #pragma unroll
        for (int wi = 0; wi < 8; wi++) {
            uint64_t wd = w0[wi];
            const int hbase = wi << 6;            // natural word order
            while (wd) {
                const int d = hbase + __builtin_ctzll(wd);
                wd &= wd - 1;
                ww |= (uint64_t)(uint32_t)d << (kk * 16);
                kk++;
                if (kk == 4) {
                    if (slot < MAXREC) {
                        uint4 q; q.x = (uint32_t)(tid | (4 << 16)); q.y = 0;
                        q.z = (uint32_t)ww; q.w = (uint32_t)(ww >> 32);
                        evl[slot] = q;
                    }
                    slot++; kk = 0; ww = 0;
                }
            }
        }
        if (kk) {
            if (slot < MAXREC) {
                uint4 q; q.x = (uint32_t)(tid | (kk << 16)); q.y = 0;
                q.z = (uint32_t)ww; q.w = (uint32_t)(ww >> 32);
                evl[slot] = q;
            }
        }
    }
    __syncthreads();

    // ---- phase 3: event-driven LIF2, time-parallel with warmup ------------
    const int nrec = (int)*nrec_p < MAXREC ? (int)*nrec_p : MAXREC;
    {
        const int ts = (grp == 0) ? 0 : tmain - WARM;
        const int te = tmain + CHUNK;
        int rs = (int)rowoff[ts];            if (rs > nrec) rs = nrec;
        int re = (grp == NGRP - 1) ? nrec : (int)rowoff[te];
        if (re > nrec) re = nrec;

        const float bb0 = b2[tig], bb1 = b2[tig + 256];
        float v0 = 0.f, v1 = 0.f;
        int cnt0 = 0, cnt1 = 0;
        int tprev = ts - 1;
        int pt = -1; v2f pg = {0.f, 0.f}; bool pend = false;

#define APPLY() do {                                                      \
        const int kk = pt - tprev - 1;                                    \
        if (kk > 0) { v0 = bb0 + ldexpf(v0 - bb0, -kk);                   \
                      v1 = bb1 + ldexpf(v1 - bb1, -kk); }                 \
        const float z0 = pg.x + bb0, z1 = pg.y + bb1;                     \
        v0 = v0 + (z0 - v0) * 0.5f;                                       \
        v1 = v1 + (z1 - v1) * 0.5f;                                       \
        if (v0 >= 1.0f) { if (pt >= tmain) cnt0++; v0 = 0.0f; }           \
        if (v1 >= 1.0f) { if (pt >= tmain) cnt1++; v1 = 0.0f; }           \
        tprev = pt;                                                       \
    } while (0)

        for (int base = rs; base < re; base += 16) {
            v2f g[16]; int tt[16];
            #pragma unroll
            for (int q = 0; q < 16; q++) {
                v2f gr = {0.f, 0.f}; int trr = -2;
                if (base + q < re) {
                    const uint4 ev = evl[base + q];       // uniform LDS read
                    trr = (int)(ev.x & 511u);
                    const int cc = (int)((ev.x >> 16) & 7u);
                    const uint64_t ww = (uint64_t)ev.z | ((uint64_t)ev.w << 32);
                    #pragma unroll
                    for (int j = 0; j < 4; j++) {
                        const int d = (int)((ww >> (16 * j)) & 0xffffu);
                        const float m = (j < cc) ? 1.0f : 0.0f;
                        const v2f wvv = W2Tp[(size_t)d * 256 + tig];  // always issued
                        gr = gr + v2f{m, m} * wvv;
                    }
                }
                g[q] = gr; tt[q] = trr;
            }
            #pragma unroll
            for (int q = 0; q < 16; q++) {
                if (base + q >= re) break;
                const int t = tt[q];
                if (pend && t == pt) { pg = pg + g[q]; }
                else { if (pend) APPLY(); pt = t; pg = g[q]; pend = true; }
            }
        }
        if (pend) APPLY();
#undef APPLY

        gcnt[grp * HID + tig]       = (float)cnt0;
        gcnt[grp * HID + tig + 256] = (float)cnt1;
    }
    __syncthreads();

    if (tid < HID)
        feat[tid] = (gcnt[0 * HID + tid] + gcnt[1 * HID + tid]
                   + gcnt[2 * HID + tid] + gcnt[3 * HID + tid])
                    * (1.0f / (float)NT);
    __syncthreads();

    // ---- phase 4: head — wave ww (<12) computes class ww ------------------
    if (wv < NCLS) {
        float acc = 0.f;
        #pragma unroll
        for (int i = 0; i < HID / 64; i++)
            acc = fmaf(feat[lane + i * 64], Wh[(size_t)wv * HID + lane + i * 64], acc);
        #pragma unroll
        for (int off = 32; off > 0; off >>= 1) acc += __shfl_down(acc, off);
        if (lane == 0) out[(size_t)b * NCLS + wv] = acc + bh[wv];
    }
}

// ---------------------------------------------------------------------------
extern "C" void kernel_launch(void* const* d_in, const int* in_sizes, int n_in,
                              void* d_out, int out_size, void* d_ws, size_t ws_size,
                              hipStream_t stream) {
    const float* x  = (const float*)d_in[0];
    const float* W1 = (const float*)d_in[1];
    const float* b1 = (const float*)d_in[2];
    const float* W2 = (const float*)d_in[3];
    const float* b2 = (const float*)d_in[4];
    const float* Wh = (const float*)d_in[5];
    const float* bh = (const float*)d_in[6];
    float* out = (float*)d_out;

    // Workspace: W2Tp (1 MB) + global spike bitmap (8 MB).
    char* ws = (char*)d_ws;
    v2f*      W2Tp = (v2f*)ws;
    uint64_t* bmg  = (uint64_t*)(ws + (1u << 20));

    hipLaunchKernelGGL(w2pt_kernel, dim3(HID / 32, 256 / 32), dim3(256), 0, stream,
                       W2, W2Tp);
    hipLaunchKernelGGL(snn_fused_kernel, dim3(NB), dim3(1024), 0, stream,
                       x, W1, b1, W2Tp, b2, Wh, bh, bmg, out);
}

// Round 10
// 290.064 us; speedup vs baseline: 1.6746x; 1.6746x over previous
//
#include <hip/hip_runtime.h>
#include <cstdint>
#include <cstddef>

// Problem constants (fixed by reference setup_inputs):
//   b=256, t=512, in_dim=30, hidden=512, n_cls=12, TAU=2, V_TH=1
#define NB 256
#define NT 512
#define IND 30
#define HID 512
#define NCLS 12
#define MAXREC 640      // per-b event record slots (16 B each, cnt<=4 per record)
#define NGRP 4          // t-chunks per b (one 256-thread block each)
#define CHUNK 128       // NT / NGRP
#define WARM 32         // warmup steps: v-error decays 0.5^32 -> ~1e-9
#define CROWS 32        // x rows per staged LDS chunk
#define NCHUNK 5        // (CHUNK + WARM) / CROWS

typedef float v2f __attribute__((ext_vector_type(2)));
typedef float v4f __attribute__((ext_vector_type(4)));

// ---------------------------------------------------------------------------
// W2 pair-transpose: W2Tp[d*256 + j] = {W2[j][d], W2[j+256][d]}.
// Block (0,0) also zeroes the per-b completion counters (every launch,
// before the mega kernel runs -> graph-replay safe by stream ordering).
// ---------------------------------------------------------------------------
__global__ __launch_bounds__(256) void w2pt_kernel(
    const float* __restrict__ W2, v2f* __restrict__ W2Tp,
    uint32_t* __restrict__ cnt)
{
    __shared__ float ta[32][33];
    __shared__ float tb[32][33];
    if (blockIdx.x == 0 && blockIdx.y == 0) cnt[threadIdx.x] = 0;
    const int d0 = blockIdx.x * 32;
    const int j0 = blockIdx.y * 32;
    const int tx = threadIdx.x & 31;
    const int ty = threadIdx.x >> 5;
    #pragma unroll
    for (int i = 0; i < 32; i += 8) {
        ta[ty + i][tx] = W2[(size_t)(j0 + ty + i) * HID + (d0 + tx)];
        tb[ty + i][tx] = W2[(size_t)(j0 + 256 + ty + i) * HID + (d0 + tx)];
    }
    __syncthreads();
    #pragma unroll
    for (int i = 0; i < 32; i += 8)
        W2Tp[(size_t)(d0 + ty + i) * 256 + (j0 + tx)] = v2f{ta[tx][ty + i], tb[tx][ty + i]};
}

// ---------------------------------------------------------------------------
// Mega kernel: grid (NB, NGRP), 256 threads (the RA shape proven spill-free).
// Part 1 (all blocks): r7's lif1 verbatim — block (b,grp) scans
//   t in [128g-32, 128g+128) (32-step warmup reconverges the LIF recurrence),
//   x staged in double-buffered 32-row LDS chunks, spike ballots stored to
//   the global bitmap as ulonglong2 (words wg*2, wg*2+1).
// Part 2 (last-arriving block of each b only, via device-scope counter):
//   inline tail — pack bitmap -> event records, event-driven layer-2 LIF
//   over the full timeline (exact, integer counts), head GEMV.
//   Tails overlap with other b's lif1 work.
// ---------------------------------------------------------------------------
__global__ __launch_bounds__(256, 1) void snn_mega_kernel(
    const float* __restrict__ x,     // (NB, NT, IND)
    const float* __restrict__ W1,    // (HID, IND)
    const float* __restrict__ b1,    // (HID)
    const v2f*  __restrict__ W2Tp,   // (HID d, 256 j) pairs
    const float* __restrict__ b2,    // (HID)
    const float* __restrict__ Wh,    // (NCLS, HID)
    const float* __restrict__ bh,    // (NCLS)
    uint64_t* __restrict__ bmg,      // (NB, NT, 8) spike bitmap
    uint32_t* __restrict__ cnt,      // (NB) completion counters
    float* __restrict__ out)         // (NB, NCLS)
{
    __shared__ __align__(16) float xs[2][CROWS * 32];   // 8 KB (lif1 x stage)
    __shared__ uint32_t sbuf[2][NT];      // 4 KB (tail scan)
    __shared__ uint4    evl[MAXREC];      // 10 KB (tail events)
    __shared__ float    feat[HID];        // 2 KB
    __shared__ uint32_t nrec_s;
    __shared__ int      lastflag;

    const int b    = blockIdx.x;
    const int grp  = blockIdx.y;
    const int tid  = threadIdx.x;
    const int lane = tid & 63;
    const int wg   = tid >> 6;            // wave 0..3

    // ================= part 1: layer-1 LIF scan (r7 verbatim) ==============
    {
        v2f wpk[IND];                     // {W1[h0][j], W1[h1][j]} -> 60 VGPRs
        {
            const float* wa = W1 + (size_t)tid * IND;
            const float* wb = W1 + (size_t)(tid + 256) * IND;
            #pragma unroll
            for (int j = 0; j < IND; j++) wpk[j] = v2f{wa[j], wb[j]};
        }
        const v2f bias = {b1[tid], b1[tid + 256]};

        const float* __restrict__ xb = x + (size_t)b * NT * IND;
        const float* xend = x + (size_t)NB * NT * IND - 2;  // clamp tail v2f
        const int trow0 = wg * 8 + (lane >> 3);
        const int scol  = (lane & 7) * 4;
        const int tmain  = grp * CHUNK;
        const int tstart = tmain - WARM;

        auto load_x = [&](int tb_, v2f& u0, v2f& u1) {
            int tr = tb_ + trow0;
            tr = tr < 0 ? 0 : tr;
            const float* s = xb + (size_t)tr * IND + scol;
            u0 = *(const v2f*)s;
            const float* s2 = s + 2;
            if (s2 > xend) s2 = xend;
            u1 = *(const v2f*)s2;
        };

        {   // prologue: stage chunk 0
            v2f u0, u1;
            load_x(tstart, u0, u1);
            float* dst = &xs[0][trow0 * 32 + scol];
            *(v2f*)dst = u0;
            *(v2f*)(dst + 2) = u1;
        }
        __syncthreads();

        v2f v = {0.f, 0.f};
        for (int k = 0; k < NCHUNK; k++) {
            v2f u0, u1;
            if (k < NCHUNK - 1) load_x(tstart + (k + 1) * CROWS, u0, u1);

            const bool wr = (k > 0);          // chunk 0 = warmup
            const float* xrow = &xs[k & 1][0];
            for (int r = 0; r < CROWS; r++) {
                const v4f* xr = (const v4f*)(xrow + r * 32);
                v4f q[8];
                #pragma unroll
                for (int m = 0; m < 8; m++) q[m] = xr[m];
                v2f a[6] = {bias, {0.f,0.f}, {0.f,0.f}, {0.f,0.f}, {0.f,0.f}, {0.f,0.f}};
                #pragma unroll
                for (int j = 0; j < IND; j++) {
                    const float sx = q[j >> 2][j & 3];
                    a[j % 6] = __builtin_elementwise_fma(v2f{sx, sx}, wpk[j], a[j % 6]);
                }
                const v2f z = ((a[0] + a[1]) + (a[2] + a[3])) + (a[4] + a[5]);
                v = v + (z - v) * 0.5f;           // charge (tau=2)
                const bool s0 = v.x >= 1.0f;
                const bool s1 = v.y >= 1.0f;
                const unsigned long long m0 = __ballot(s0);
                const unsigned long long m1 = __ballot(s1);
                if (s0) v.x = 0.0f;
                if (s1) v.y = 0.0f;
                if (wr && lane == 0) {
                    const int t = tmain + (k - 1) * CROWS + r;
                    ulonglong2 st; st.x = m0; st.y = m1;
                    *(ulonglong2*)(bmg + ((size_t)b * NT + t) * 8 + wg * 2) = st;
                }
            }
            if (k == 0 && grp == 0) v = v2f{0.f, 0.f};

            if (k < NCHUNK - 1) {
                float* dst = &xs[(k + 1) & 1][trow0 * 32 + scol];
                *(v2f*)dst = u0;
                *(v2f*)(dst + 2) = u1;
            }
            __syncthreads();
        }
    }

    // ============== completion handshake: last block runs tail =============
    __threadfence();                       // publish this block's bitmap rows
    __syncthreads();                       // order all threads' fences before
    if (tid == 0) lastflag = (atomicAdd(&cnt[b], 1u) == NGRP - 1);
    __syncthreads();
    if (!lastflag) return;
    __threadfence();                       // acquire: see siblings' rows

    // ================= part 2: inline tail (256 threads) ===================
    const int t0 = tid, t1 = tid + 256;

    // ---- pack: bitmap -> event records ------------------------------------
    uint64_t w0[8], w1[8];
    {
        const uint4* p0 = (const uint4*)(bmg + ((size_t)b * NT + t0) * 8);
        const uint4* p1 = (const uint4*)(bmg + ((size_t)b * NT + t1) * 8);
        #pragma unroll
        for (int k = 0; k < 4; k++) {
            const uint4 qa = p0[k];
            w0[2 * k]     = (uint64_t)qa.x | ((uint64_t)qa.y << 32);
            w0[2 * k + 1] = (uint64_t)qa.z | ((uint64_t)qa.w << 32);
            const uint4 qb = p1[k];
            w1[2 * k]     = (uint64_t)qb.x | ((uint64_t)qb.y << 32);
            w1[2 * k + 1] = (uint64_t)qb.z | ((uint64_t)qb.w << 32);
        }
    }
    int c0 = 0, c1 = 0;
    #pragma unroll
    for (int k = 0; k < 8; k++) { c0 += __builtin_popcountll(w0[k]); c1 += __builtin_popcountll(w1[k]); }
    const int r0 = (c0 + 3) >> 2;
    const int r1 = (c1 + 3) >> 2;

    sbuf[0][t0] = (uint32_t)r0; sbuf[0][t1] = (uint32_t)r1;
    __syncthreads();
    int cur = 0;
    for (int off = 1; off < NT; off <<= 1) {
        const uint32_t a = sbuf[cur][t0] + (t0 >= off ? sbuf[cur][t0 - off] : 0u);
        const uint32_t c = sbuf[cur][t1] + (t1 >= off ? sbuf[cur][t1 - off] : 0u);
        sbuf[cur ^ 1][t0] = a; sbuf[cur ^ 1][t1] = c;
        __syncthreads();
        cur ^= 1;
    }
    const int excl0 = (int)sbuf[cur][t0] - r0;
    const int excl1 = (int)sbuf[cur][t1] - r1;
    if (tid == 0) nrec_s = sbuf[cur][NT - 1];

    auto emit = [&](const uint64_t* wv, int t, int slot) {
        int kk = 0; uint64_t ww = 0;
        #pragma unroll
        for (int wi = 0; wi < 8; wi++) {
            uint64_t wd = wv[wi];
            const int hbase = ((wi >> 1) << 6) + ((wi & 1) << 8);  // paired words
            while (wd) {
                const int d = hbase + __builtin_ctzll(wd);
                wd &= wd - 1;
                ww |= (uint64_t)(uint32_t)d << (kk * 16);
                kk++;
                if (kk == 4) {
                    if (slot < MAXREC) {
                        uint4 q; q.x = (uint32_t)(t | (4 << 16)); q.y = 0;
                        q.z = (uint32_t)ww; q.w = (uint32_t)(ww >> 32);
                        evl[slot] = q;
                    }
                    slot++; kk = 0; ww = 0;
                }
            }
        }
        if (kk) {
            if (slot < MAXREC) {
                uint4 q; q.x = (uint32_t)(t | (kk << 16)); q.y = 0;
                q.z = (uint32_t)ww; q.w = (uint32_t)(ww >> 32);
                evl[slot] = q;
            }
        }
    };
    emit(w0, t0, excl0);
    emit(w1, t1, excl1);
    __syncthreads();

    // ---- event-driven layer-2 LIF, full timeline (exact) ------------------
    const int nrec = (int)nrec_s < MAXREC ? (int)nrec_s : MAXREC;
    {
        const float bb0 = b2[tid], bb1 = b2[tid + 256];
        float v0 = 0.f, v1 = 0.f;
        int cnt0 = 0, cnt1 = 0;
        int tprev = -1;
        int pt = -1; v2f pg = {0.f, 0.f}; bool pend = false;

#define APPLY() do {                                                      \
        const int kk = pt - tprev - 1;                                    \
        if (kk > 0) { v0 = bb0 + ldexpf(v0 - bb0, -kk);                   \
                      v1 = bb1 + ldexpf(v1 - bb1, -kk); }                 \
        const float z0 = pg.x + bb0, z1 = pg.y + bb1;                     \
        v0 = v0 + (z0 - v0) * 0.5f;                                       \
        v1 = v1 + (z1 - v1) * 0.5f;                                       \
        if (v0 >= 1.0f) { cnt0++; v0 = 0.0f; }                            \
        if (v1 >= 1.0f) { cnt1++; v1 = 0.0f; }                            \
        tprev = pt;                                                       \
    } while (0)

        for (int base = 0; base < nrec; base += 16) {
            v2f g[16]; int tt[16];
            #pragma unroll
            for (int q = 0; q < 16; q++) {
                v2f gr = {0.f, 0.f}; int trr = -2;
                if (base + q < nrec) {
                    const uint4 ev = evl[base + q];       // uniform LDS read
                    trr = (int)(ev.x & 511u);
                    const int cc = (int)((ev.x >> 16) & 7u);
                    const uint64_t ww = (uint64_t)ev.z | ((uint64_t)ev.w << 32);
                    #pragma unroll
                    for (int j = 0; j < 4; j++) {
                        const int d = (int)((ww >> (16 * j)) & 0xffffu);
                        const float m = (j < cc) ? 1.0f : 0.0f;
                        const v2f wvv = W2Tp[(size_t)d * 256 + tid];  // always issued
                        gr = gr + v2f{m, m} * wvv;
                    }
                }
                g[q] = gr; tt[q] = trr;
            }
            #pragma unroll
            for (int q = 0; q < 16; q++) {
                if (base + q >= nrec) break;
                const int t = tt[q];
                if (pend && t == pt) { pg = pg + g[q]; }
                else { if (pend) APPLY(); pt = t; pg = g[q]; pend = true; }
            }
        }
        if (pend) APPLY();
#undef APPLY

        feat[tid]       = (float)cnt0 * (1.0f / (float)NT);
        feat[tid + 256] = (float)cnt1 * (1.0f / (float)NT);
    }
    __syncthreads();

    // ---- head: wave wg computes classes 3wg..3wg+2 ------------------------
    float acc[3] = {0.f, 0.f, 0.f};
    #pragma unroll
    for (int i = 0; i < HID / 64; i++) {
        const float f = feat[lane + i * 64];
        #pragma unroll
        for (int cc = 0; cc < 3; cc++)
            acc[cc] = fmaf(f, Wh[(size_t)(wg * 3 + cc) * HID + lane + i * 64], acc[cc]);
    }
    #pragma unroll
    for (int cc = 0; cc < 3; cc++) {
        float s = acc[cc];
        #pragma unroll
        for (int off = 32; off > 0; off >>= 1) s += __shfl_down(s, off);
        if (lane == 0) out[(size_t)b * NCLS + wg * 3 + cc] = s + bh[wg * 3 + cc];
    }
}

// ---------------------------------------------------------------------------
extern "C" void kernel_launch(void* const* d_in, const int* in_sizes, int n_in,
                              void* d_out, int out_size, void* d_ws, size_t ws_size,
                              hipStream_t stream) {
    const float* x  = (const float*)d_in[0];
    const float* W1 = (const float*)d_in[1];
    const float* b1 = (const float*)d_in[2];
    const float* W2 = (const float*)d_in[3];
    const float* b2 = (const float*)d_in[4];
    const float* Wh = (const float*)d_in[5];
    const float* bh = (const float*)d_in[6];
    float* out = (float*)d_out;

    // Workspace: W2Tp (1 MB) + bitmap (8 MB) + counters (1 KB).
    char* ws = (char*)d_ws;
    v2f*      W2Tp = (v2f*)ws;
    uint64_t* bmg  = (uint64_t*)(ws + (1u << 20));
    uint32_t* cnt  = (uint32_t*)(ws + (9u << 20));

    hipLaunchKernelGGL(w2pt_kernel, dim3(HID / 32, 256 / 32), dim3(256), 0, stream,
                       W2, W2Tp, cnt);
    hipLaunchKernelGGL(snn_mega_kernel, dim3(NB, NGRP), dim3(256), 0, stream,
                       x, W1, b1, W2Tp, b2, Wh, bh, bmg, cnt, out);
}

// Round 11
// 148.668 us; speedup vs baseline: 3.2673x; 1.9511x over previous
//
#include <hip/hip_runtime.h>
#include <cstdint>
#include <cstddef>

// Problem constants (fixed by reference setup_inputs):
//   b=256, t=512, in_dim=30, hidden=512, n_cls=12, TAU=2, V_TH=1
#define NB 256
#define NT 512
#define IND 30
#define HID 512
#define NCLS 12
#define MAXREC 640      // per-b event record slots (16 B each, cnt<=4 per record)
#define NGRP 4          // t-chunks per b (one 256-thread block each)
#define CHUNK 128       // NT / NGRP
#define WARM 32         // warmup steps: v-error decays 0.5^32 -> ~1e-9

typedef float v2f __attribute__((ext_vector_type(2)));

// ---------------------------------------------------------------------------
// lif1 + W2-transpose mega-launch: grid (NB, NGRP+1), 256 threads.
//
// Plane y < NGRP: layer-1 LIF scan (the r7 256-thread spill-free shape,
//   VGPR=60 proven). Block (b,grp) scans t in [128g-32, 128g+128); the
//   32-step warmup from v=0 reconverges the recurrence (decay 0.5/step +
//   hard resets). NEW vs r7: x rows are read DIRECTLY from global with
//   wave-uniform addresses -> the compiler's uniformity analysis emits
//   s_load into SGPRs (scalar pipe), freeing the LDS pipe that bounded r7
//   (8 uniform ds_read_b128/step/wave ~= 96 cyc x 16 waves/CU = the 88 us).
//   v_pk_fma then consumes the SGPR x-pair as src0 directly.
//   2-step A/B software pipeline hides the s_load latency.
// Plane y == NGRP: W2 pair-transpose (128 active blocks):
//   W2Tp[d*256 + j] = {W2[j][d], W2[j+256][d]}  (folded in to save a launch).
// ---------------------------------------------------------------------------
__global__ __launch_bounds__(256, 1) void lif1w_kernel(
    const float* __restrict__ x,     // (NB, NT, IND)
    const float* __restrict__ W1,    // (HID, IND)
    const float* __restrict__ b1,    // (HID)
    const float* __restrict__ W2,    // (HID, HID)
    uint64_t* __restrict__ bmg,      // (NB, NT, 8)
    v2f* __restrict__ W2Tp)          // (HID d, 256 j) pairs
{
    if (blockIdx.y == NGRP) {
        // ---- W2 pair-transpose plane --------------------------------------
        __shared__ float ta[32][33];
        __shared__ float tb[32][33];
        const int bx = blockIdx.x;
        if (bx >= (HID / 32) * (256 / 32)) return;   // 128 active blocks
        const int d0 = (bx & 15) * 32;
        const int j0 = (bx >> 4) * 32;
        const int tx = threadIdx.x & 31;
        const int ty = threadIdx.x >> 5;
        #pragma unroll
        for (int i = 0; i < 32; i += 8) {
            ta[ty + i][tx] = W2[(size_t)(j0 + ty + i) * HID + (d0 + tx)];
            tb[ty + i][tx] = W2[(size_t)(j0 + 256 + ty + i) * HID + (d0 + tx)];
        }
        __syncthreads();
        #pragma unroll
        for (int i = 0; i < 32; i += 8)
            W2Tp[(size_t)(d0 + ty + i) * 256 + (j0 + tx)]
                = v2f{ta[tx][ty + i], tb[tx][ty + i]};
        return;
    }

    // ---- layer-1 LIF scan ---------------------------------------------------
    const int b    = blockIdx.x;
    const int grp  = blockIdx.y;
    const int tid  = threadIdx.x;
    const int lane = tid & 63;
    const int wg   = tid >> 6;            // wave 0..3

    // j-paired weights for h0=tid, h1=tid+256 (rows are 120 B -> 8-B aligned).
    v2f wA[15], wB[15];                   // 60 VGPRs (the r7-proven budget)
    {
        const v2f* pa = (const v2f*)(W1 + (size_t)tid * IND);
        const v2f* pb = (const v2f*)(W1 + (size_t)(tid + 256) * IND);
        #pragma unroll
        for (int p = 0; p < 15; p++) { wA[p] = pa[p]; wB[p] = pb[p]; }
    }
    const float biasA = b1[tid], biasB = b1[tid + 256];

    const int tmain  = grp * CHUNK;
    const int tstart = (grp == 0) ? 0 : tmain - WARM;
    const int tend   = tmain + CHUNK;
    const float* __restrict__ xb = x + (size_t)b * NT * IND;
    uint64_t* __restrict__ bout = bmg + (size_t)b * NT * 8 + wg * 2;

    // One LIF step from the (wave-uniform) x row XR[0..14] (v2f pairs).
    // pk_fma: src0 = x pair (SGPR pair when scalarized), src1 = weight pair.
#define LIF_STEP(XR, T) do {                                              \
        v2f aA0 = {biasA, 0.f}, aA1 = {0.f, 0.f}, aA2 = {0.f, 0.f};       \
        v2f aB0 = {biasB, 0.f}, aB1 = {0.f, 0.f}, aB2 = {0.f, 0.f};       \
        _Pragma("unroll")                                                 \
        for (int p = 0; p < 15; p += 3) {                                 \
            aA0 = __builtin_elementwise_fma(XR[p    ], wA[p    ], aA0);   \
            aB0 = __builtin_elementwise_fma(XR[p    ], wB[p    ], aB0);   \
            aA1 = __builtin_elementwise_fma(XR[p + 1], wA[p + 1], aA1);   \
            aB1 = __builtin_elementwise_fma(XR[p + 1], wB[p + 1], aB1);   \
            aA2 = __builtin_elementwise_fma(XR[p + 2], wA[p + 2], aA2);   \
            aB2 = __builtin_elementwise_fma(XR[p + 2], wB[p + 2], aB2);   \
        }                                                                 \
        const v2f sA = (aA0 + aA1) + aA2;                                 \
        const v2f sB = (aB0 + aB1) + aB2;                                 \
        const float zA = sA.x + sA.y;                                     \
        const float zB = sB.x + sB.y;                                     \
        vA = vA + (zA - vA) * 0.5f;       /* charge (tau=2) */            \
        vB = vB + (zB - vB) * 0.5f;                                       \
        const bool s0 = vA >= 1.0f;                                       \
        const bool s1 = vB >= 1.0f;                                       \
        const unsigned long long m0 = __ballot(s0);                       \
        const unsigned long long m1 = __ballot(s1);                       \
        if (s0) vA = 0.0f;                                                \
        if (s1) vB = 0.0f;                                                \
        if ((T) >= tmain && lane == 0) {                                  \
            ulonglong2 st; st.x = m0; st.y = m1;                          \
            *(ulonglong2*)(bout + (size_t)(T) * 8) = st;                  \
        }                                                                 \
    } while (0)

#define LOAD_XROW(DST, T) do {                                            \
        const v2f* _p = (const v2f*)(xb + (size_t)(T) * IND);             \
        _Pragma("unroll")                                                 \
        for (int _k = 0; _k < 15; _k++) DST[_k] = _p[_k];                 \
    } while (0)

    float vA = 0.f, vB = 0.f;
    v2f XA[15], XB[15];
    LOAD_XROW(XA, tstart);
    for (int t = tstart; t < tend; t += 2) {
        LOAD_XROW(XB, t + 1);                         // t+1 <= tend-1 <= 511
        LIF_STEP(XA, t);
        const int t2 = (t + 2 < NT) ? t + 2 : NT - 1; // clamp final prefetch
        LOAD_XROW(XA, t2);
        LIF_STEP(XB, t + 1);
    }
#undef LOAD_XROW
#undef LIF_STEP
}

// ---------------------------------------------------------------------------
// tail: pack (global bitmap -> event records) + event-driven LIF2 + head.
// Byte-for-byte the r7 (151 us) tail. Bitmap word wi covers
// h = (wi>>1)*64 + (wi&1)*256 + bit  (lif1's paired ulonglong2 store).
// ---------------------------------------------------------------------------
__global__ __launch_bounds__(1024) void snn_tail_kernel(
    const uint64_t* __restrict__ bmg, // (NB, NT, 8)
    const v2f*  __restrict__ W2Tp,    // (HID d, 256 j) pairs
    const float* __restrict__ b2,     // (HID)
    const float* __restrict__ Wh,     // (NCLS, HID)
    const float* __restrict__ bh,     // (NCLS)
    float* __restrict__ out)          // (NB, NCLS)
{
    __shared__ uint32_t sbuf[2][NT];      // 4 KB record-count scan
    __shared__ uint16_t rowoff[NT];       // 1 KB per-row record offsets
    __shared__ uint4    evl[MAXREC];      // 10 KB packed event records
    __shared__ float    gcnt[NGRP][HID];  // 8 KB per-group spike counts
    __shared__ float    feat[HID];        // 2 KB
    __shared__ uint32_t nrec_s;

    const int b    = blockIdx.x;
    const int tid  = threadIdx.x;
    const int grp  = tid >> 8;            // 0..3
    const int tig  = tid & 255;
    const int lane = tid & 63;
    const int tmain = grp * CHUNK;

    // ---- pack ------------------------------------------------------------
    uint64_t w0[8];
    int rcnt = 0;
    if (tid < NT) {
        const uint4* p = (const uint4*)(bmg + ((size_t)b * NT + tid) * 8);
        int cpop = 0;
        #pragma unroll
        for (int k = 0; k < 4; k++) {
            const uint4 q = p[k];
            w0[2 * k]     = (uint64_t)q.x | ((uint64_t)q.y << 32);
            w0[2 * k + 1] = (uint64_t)q.z | ((uint64_t)q.w << 32);
        }
        #pragma unroll
        for (int k = 0; k < 8; k++) cpop += __builtin_popcountll(w0[k]);
        rcnt = (cpop + 3) >> 2;
        sbuf[0][tid] = (uint32_t)rcnt;
    }
    __syncthreads();
    int cur = 0;
    for (int off = 1; off < NT; off <<= 1) {
        uint32_t a = 0;
        if (tid < NT) a = sbuf[cur][tid] + (tid >= off ? sbuf[cur][tid - off] : 0u);
        if (tid < NT) sbuf[cur ^ 1][tid] = a;
        __syncthreads();
        cur ^= 1;
    }
    int excl = 0;
    if (tid < NT) {
        excl = (int)sbuf[cur][tid] - rcnt;
        rowoff[tid] = (uint16_t)(excl < 65535 ? excl : 65535);
        if (tid == NT - 1) nrec_s = sbuf[cur][NT - 1];
    }
    if (tid < NT) {
        int slot = excl, kk = 0; uint64_t ww = 0;
        #pragma unroll
        for (int wi = 0; wi < 8; wi++) {
            uint64_t wd = w0[wi];
            const int hbase = ((wi >> 1) << 6) + ((wi & 1) << 8);  // paired words
            while (wd) {
                const int d = hbase + __builtin_ctzll(wd);
                wd &= wd - 1;
                ww |= (uint64_t)(uint32_t)d << (kk * 16);
                kk++;
                if (kk == 4) {
                    if (slot < MAXREC) {
                        uint4 q; q.x = (uint32_t)(tid | (4 << 16)); q.y = 0;
                        q.z = (uint32_t)ww; q.w = (uint32_t)(ww >> 32);
                        evl[slot] = q;
                    }
                    slot++; kk = 0; ww = 0;
                }
            }
        }
        if (kk) {
            if (slot < MAXREC) {
                uint4 q; q.x = (uint32_t)(tid | (kk << 16)); q.y = 0;
                q.z = (uint32_t)ww; q.w = (uint32_t)(ww >> 32);
                evl[slot] = q;
            }
        }
    }
    __syncthreads();

    // ---- event-driven LIF2, time-parallel with warmup ---------------------
    const int nrec = (int)nrec_s < MAXREC ? (int)nrec_s : MAXREC;
    {
        const int ts = (grp == 0) ? 0 : tmain - WARM;
        const int te = tmain + CHUNK;
        int rs = (int)rowoff[ts];            if (rs > nrec) rs = nrec;
        int re = (grp == NGRP - 1) ? nrec : (int)rowoff[te];
        if (re > nrec) re = nrec;

        const float bb0 = b2[tig], bb1 = b2[tig + 256];
        float v0 = 0.f, v1 = 0.f;
        int cnt0 = 0, cnt1 = 0;
        int tprev = ts - 1;
        int pt = -1; v2f pg = {0.f, 0.f}; bool pend = false;

#define APPLY() do {                                                      \
        const int kk = pt - tprev - 1;                                    \
        if (kk > 0) { v0 = bb0 + ldexpf(v0 - bb0, -kk);                   \
                      v1 = bb1 + ldexpf(v1 - bb1, -kk); }                 \
        const float z0 = pg.x + bb0, z1 = pg.y + bb1;                     \
        v0 = v0 + (z0 - v0) * 0.5f;                                       \
        v1 = v1 + (z1 - v1) * 0.5f;                                       \
        if (v0 >= 1.0f) { if (pt >= tmain) cnt0++; v0 = 0.0f; }           \
        if (v1 >= 1.0f) { if (pt >= tmain) cnt1++; v1 = 0.0f; }           \
        tprev = pt;                                                       \
    } while (0)

        for (int base = rs; base < re; base += 16) {
            v2f g[16]; int tt[16];
            #pragma unroll
            for (int q = 0; q < 16; q++) {
                v2f gr = {0.f, 0.f}; int trr = -2;
                if (base + q < re) {
                    const uint4 ev = evl[base + q];       // uniform LDS read
                    trr = (int)(ev.x & 511u);
                    const int cc = (int)((ev.x >> 16) & 7u);
                    const uint64_t ww = (uint64_t)ev.z | ((uint64_t)ev.w << 32);
                    #pragma unroll
                    for (int j = 0; j < 4; j++) {
                        const int d = (int)((ww >> (16 * j)) & 0xffffu);
                        const float m = (j < cc) ? 1.0f : 0.0f;
                        const v2f wv = W2Tp[(size_t)d * 256 + tig];  // always issued
                        gr = gr + v2f{m, m} * wv;
                    }
                }
                g[q] = gr; tt[q] = trr;
            }
            #pragma unroll
            for (int q = 0; q < 16; q++) {
                if (base + q >= re) break;
                const int t = tt[q];
                if (pend && t == pt) { pg = pg + g[q]; }
                else { if (pend) APPLY(); pt = t; pg = g[q]; pend = true; }
            }
        }
        if (pend) APPLY();
#undef APPLY

        gcnt[grp][tig]       = (float)cnt0;
        gcnt[grp][tig + 256] = (float)cnt1;
    }
    __syncthreads();

    if (tid < HID)
        feat[tid] = (gcnt[0][tid] + gcnt[1][tid] + gcnt[2][tid] + gcnt[3][tid])
                    * (1.0f / (float)NT);
    __syncthreads();

    // ---- head: wave ww (<12) computes class ww ----------------------------
    const int ww = tid >> 6;              // 0..15
    if (ww < NCLS) {
        float acc = 0.f;
        #pragma unroll
        for (int i = 0; i < HID / 64; i++)
            acc = fmaf(feat[lane + i * 64], Wh[(size_t)ww * HID + lane + i * 64], acc);
        #pragma unroll
        for (int off = 32; off > 0; off >>= 1) acc += __shfl_down(acc, off);
        if (lane == 0) out[(size_t)b * NCLS + ww] = acc + bh[ww];
    }
}

// ---------------------------------------------------------------------------
extern "C" void kernel_launch(void* const* d_in, const int* in_sizes, int n_in,
                              void* d_out, int out_size, void* d_ws, size_t ws_size,
                              hipStream_t stream) {
    const float* x  = (const float*)d_in[0];
    const float* W1 = (const float*)d_in[1];
    const float* b1 = (const float*)d_in[2];
    const float* W2 = (const float*)d_in[3];
    const float* b2 = (const float*)d_in[4];
    const float* Wh = (const float*)d_in[5];
    const float* bh = (const float*)d_in[6];
    float* out = (float*)d_out;

    // Workspace: W2Tp (1 MB) + global spike bitmap (8 MB).
    char* ws = (char*)d_ws;
    v2f*      W2Tp = (v2f*)ws;
    uint64_t* bmg  = (uint64_t*)(ws + (1u << 20));

    hipLaunchKernelGGL(lif1w_kernel, dim3(NB, NGRP + 1), dim3(256), 0, stream,
                       x, W1, b1, W2, bmg, W2Tp);
    hipLaunchKernelGGL(snn_tail_kernel, dim3(NB), dim3(1024), 0, stream,
                       bmg, W2Tp, b2, Wh, bh, out);
}